// Round 1
// 4189.742 us; speedup vs baseline: 2.7572x; 2.7572x over previous
//
#include <hip/hip_runtime.h>
#include <math.h>

#define KNN 20
#define NPTS 4096
#define NB 8

__device__ __forceinline__ bool lexless(float d1, int i1, float d2, int i2) {
    return d1 < d2 || (d1 == d2 && i1 < i2);
}

// ---------------------------------------------------------------- concat x|pos
__global__ __launch_bounds__(256) void concat_kernel(const float* __restrict__ x,
                                                     const float* __restrict__ pos,
                                                     float* __restrict__ f0, int total) {
    int p = blockIdx.x * 256 + threadIdx.x;
    if (p < total) {
        f0[(size_t)p*6 + 0] = x[(size_t)p*3 + 0];
        f0[(size_t)p*6 + 1] = x[(size_t)p*3 + 1];
        f0[(size_t)p*6 + 2] = x[(size_t)p*3 + 2];
        f0[(size_t)p*6 + 3] = pos[(size_t)p*3 + 0];
        f0[(size_t)p*6 + 4] = pos[(size_t)p*3 + 1];
        f0[(size_t)p*6 + 5] = pos[(size_t)p*3 + 2];
    }
}

// ---------------------------------------------------------------- squared norms
template<int C>
__global__ __launch_bounds__(256) void norm_kernel(const float* __restrict__ f, int ldf,
                                                   float* __restrict__ norms, int total) {
    int p = blockIdx.x * 256 + threadIdx.x;
    if (p >= total) return;
    const float* fp = f + (size_t)p * ldf;
    float s = 0.f;
    if constexpr ((C & 3) == 0) {
#pragma unroll
        for (int k = 0; k < C; k += 4) {
            float4 v = *(const float4*)(fp + k);
            s = fmaf(v.x, v.x, s); s = fmaf(v.y, v.y, s);
            s = fmaf(v.z, v.z, s); s = fmaf(v.w, v.w, s);
        }
    } else {
#pragma unroll
        for (int k = 0; k < C; ++k) s = fmaf(fp[k], fp[k], s);
    }
    norms[p] = s;
}

// ---------------------------------------------------------------- fused tiled kNN
// Block = 256 threads handles 64 queries of one batch.
// Loop over 64-candidate tiles: stage features, 64x64 dot GEMM (4x4 micro-tiles),
// distances to LDS, then 4 threads/query scan disjoint quarters with private
// top-20 lists; single 4-way merge at the end.
template<int C>
__global__ __launch_bounds__(256) void knn_tile_kernel(const float* __restrict__ f, int ldf,
                                                       const float* __restrict__ norms,
                                                       int* __restrict__ idx) {
    const int q0    = blockIdx.x * 64;      // global query base
    const int b     = q0 >> 12;             // batch
    const int qloc0 = q0 & (NPTS - 1);
    const int tid   = threadIdx.x;
    const int tx    = tid & 15, ty = tid >> 4;

    union __align__(16) SM {
        struct {
            float Qs[C][64];
            float Cs[C][64];
            float Ds[64][65];
            float cn[64];
        } a;
        struct {
            float md[64][4 * KNN];
            int   mi[64][4 * KNN];
        } m;
    };
    __shared__ SM sm;

    const float* fb = f + (size_t)b * NPTS * ldf;

    // stage query tile Qs[k][m]
    if constexpr ((C & 3) == 0) {
        int m = tid >> 2, ko = (tid & 3) * 4;
        const float* src = fb + (size_t)(qloc0 + m) * ldf;
#pragma unroll
        for (int k4 = ko; k4 < C; k4 += 16) {
            float4 v = *(const float4*)(src + k4);
            sm.a.Qs[k4 + 0][m] = v.x; sm.a.Qs[k4 + 1][m] = v.y;
            sm.a.Qs[k4 + 2][m] = v.z; sm.a.Qs[k4 + 3][m] = v.w;
        }
    } else {
        for (int e = tid; e < C * 64; e += 256) {
            int k = e >> 6, m = e & 63;
            sm.a.Qs[k][m] = fb[(size_t)(qloc0 + m) * ldf + k];
        }
    }

    const float qnr = norms[q0 + (tid & 63)];   // own query's norm (qr = tid&63)

    float bd[KNN]; int bi[KNN];
#pragma unroll
    for (int t = 0; t < KNN; ++t) { bd[t] = INFINITY; bi[t] = 0x7fffffff; }

    for (int j0 = 0; j0 < NPTS; j0 += 64) {
        __syncthreads();   // prev scan done / Qs staged before (re)filling Cs,cn

        // stage candidate tile Cs[k][j] + candidate norms
        if constexpr ((C & 3) == 0) {
            int j = tid >> 2, ko = (tid & 3) * 4;
            const float* src = fb + (size_t)(j0 + j) * ldf;
#pragma unroll
            for (int k4 = ko; k4 < C; k4 += 16) {
                float4 v = *(const float4*)(src + k4);
                sm.a.Cs[k4 + 0][j] = v.x; sm.a.Cs[k4 + 1][j] = v.y;
                sm.a.Cs[k4 + 2][j] = v.z; sm.a.Cs[k4 + 3][j] = v.w;
            }
        } else {
            for (int e = tid; e < C * 64; e += 256) {
                int k = e >> 6, j = e & 63;
                sm.a.Cs[k][j] = fb[(size_t)(j0 + j) * ldf + k];
            }
        }
        if (tid < 64) sm.a.cn[tid] = norms[(size_t)b * NPTS + j0 + tid];
        __syncthreads();

        // 64x64xC dot-product tile, 4x4 micro-tile per thread
        float acc[4][4] = {};
#pragma unroll 8
        for (int kk = 0; kk < C; ++kk) {
            float4 av = *(const float4*)&sm.a.Qs[kk][ty * 4];
            float4 bv = *(const float4*)&sm.a.Cs[kk][tx * 4];
            float a[4] = {av.x, av.y, av.z, av.w};
            float bb[4] = {bv.x, bv.y, bv.z, bv.w};
#pragma unroll
            for (int i = 0; i < 4; ++i)
#pragma unroll
                for (int j = 0; j < 4; ++j) acc[i][j] = fmaf(a[i], bb[j], acc[i][j]);
        }
#pragma unroll
        for (int i = 0; i < 4; ++i)
#pragma unroll
            for (int j = 0; j < 4; ++j)
                sm.a.Ds[ty * 4 + i][tx * 4 + j] = acc[i][j];
        __syncthreads();

        // scan: thread (grp, qr) checks candidates [grp*16, grp*16+16) of this tile
        {
            const int qr = tid & 63;
            const int jb = (tid >> 6) * 16;
#pragma unroll
            for (int jj = 0; jj < 16; ++jj) {
                float dot = sm.a.Ds[qr][jb + jj];
                float d   = qnr + sm.a.cn[jb + jj] - 2.0f * dot;
                int   jg  = j0 + jb + jj;
                if (lexless(d, jg, bd[KNN - 1], bi[KNN - 1])) {
                    float cd = d; int ci = jg;
#pragma unroll
                    for (int t = 0; t < KNN; ++t) {
                        bool sw = lexless(cd, ci, bd[t], bi[t]);
                        float nd = sw ? cd : bd[t]; int ni = sw ? ci : bi[t];
                        float od = sw ? bd[t] : cd; int oi = sw ? bi[t] : ci;
                        bd[t] = nd; bi[t] = ni; cd = od; ci = oi;
                    }
                }
            }
        }
    }
    __syncthreads();   // all scans done; a.* dead → reuse as merge buffers

    {
        const int qr = tid & 63;
        const int grp = tid >> 6;
#pragma unroll
        for (int t = 0; t < KNN; ++t) {
            sm.m.md[qr][grp * KNN + t] = bd[t];
            sm.m.mi[qr][grp * KNN + t] = bi[t];
        }
    }
    __syncthreads();

    if (tid < 64) {
        // 4-way merge of sorted 20-lists (disjoint candidate subsets)
        int p0 = 0, p1 = KNN, p2 = 2 * KNN, p3 = 3 * KNN;
        int* op = idx + (size_t)(q0 + tid) * KNN;
        for (int r = 0; r < KNN; ++r) {
            float d0 = (p0 < KNN)     ? sm.m.md[tid][p0] : INFINITY;
            int   i0 = (p0 < KNN)     ? sm.m.mi[tid][p0] : 0x7fffffff;
            float d1 = (p1 < 2 * KNN) ? sm.m.md[tid][p1] : INFINITY;
            int   i1 = (p1 < 2 * KNN) ? sm.m.mi[tid][p1] : 0x7fffffff;
            float d2 = (p2 < 3 * KNN) ? sm.m.md[tid][p2] : INFINITY;
            int   i2 = (p2 < 3 * KNN) ? sm.m.mi[tid][p2] : 0x7fffffff;
            float d3 = (p3 < 4 * KNN) ? sm.m.md[tid][p3] : INFINITY;
            int   i3 = (p3 < 4 * KNN) ? sm.m.mi[tid][p3] : 0x7fffffff;
            float bdv = d0; int biv = i0; int bg = 0;
            if (lexless(d1, i1, bdv, biv)) { bdv = d1; biv = i1; bg = 1; }
            if (lexless(d2, i2, bdv, biv)) { bdv = d2; biv = i2; bg = 2; }
            if (lexless(d3, i3, bdv, biv)) { bdv = d3; biv = i3; bg = 3; }
            op[r] = biv;
            p0 += (bg == 0); p1 += (bg == 1); p2 += (bg == 2); p3 += (bg == 3);
        }
    }
}

// ---------------------------------------------------------------- EdgeConv (wave/point)
template<int C>
__global__ __launch_bounds__(64) void edgeconv_kernel(
    const float* __restrict__ f, int ldf,
    const int* __restrict__ idx,
    const float* __restrict__ W1, const float* __restrict__ b1,
    const float* __restrict__ g,  const float* __restrict__ be,
    const float* __restrict__ W2, const float* __restrict__ b2,
    float* __restrict__ out, int ldo) {
    const int p = blockIdx.x;
    const int b = p >> 12;
    const int i = p & (NPTS - 1);
    const int c = threadIdx.x;   // output channel, 0..63
    __shared__ __align__(16) float fi_s[C];
    __shared__ __align__(16) float fj_s[KNN][C];
    __shared__ __align__(16) float h1_s[KNN][64];
    __shared__ int nidx[KNN];
    const float* fb = f + (size_t)b * NPTS * ldf;
    if (c < KNN) nidx[c] = idx[(size_t)p * KNN + c];
    if (c < C)   fi_s[c] = fb[(size_t)i * ldf + c];
    __syncthreads();
#pragma unroll
    for (int j = 0; j < KNN; ++j)
        if (c < C) fj_s[j][c] = fb[(size_t)nidx[j] * ldf + c];
    __syncthreads();
    float fir[C];
#pragma unroll
    for (int k = 0; k < C; ++k) fir[k] = fi_s[k];

    const float bn_s = (float)(1.0 / sqrt(1.0 + 1e-5));
    const float bnscale = g[c] * bn_s;
    float base = b1[c];
#pragma unroll
    for (int k = 0; k < C; ++k) base = fmaf(fir[k], W1[k * 64 + c], base);
    float acc[KNN];
#pragma unroll
    for (int j = 0; j < KNN; ++j) acc[j] = base;

    if constexpr ((C & 3) == 0) {
#pragma unroll
        for (int k = 0; k < C; k += 4) {
            float w0 = W1[(C + k + 0) * 64 + c];
            float w1 = W1[(C + k + 1) * 64 + c];
            float w2 = W1[(C + k + 2) * 64 + c];
            float w3 = W1[(C + k + 3) * 64 + c];
            float f0 = fir[k + 0], f1 = fir[k + 1], f2 = fir[k + 2], f3 = fir[k + 3];
#pragma unroll
            for (int j = 0; j < KNN; ++j) {
                float4 v = *(const float4*)&fj_s[j][k];
                acc[j] = fmaf(v.x - f0, w0, acc[j]);
                acc[j] = fmaf(v.y - f1, w1, acc[j]);
                acc[j] = fmaf(v.z - f2, w2, acc[j]);
                acc[j] = fmaf(v.w - f3, w3, acc[j]);
            }
        }
    } else {
#pragma unroll
        for (int k = 0; k < C; ++k) {
            float w = W1[(C + k) * 64 + c];
            float fik = fir[k];
#pragma unroll
            for (int j = 0; j < KNN; ++j) acc[j] = fmaf(fj_s[j][k] - fik, w, acc[j]);
        }
    }
    float bec = be[c];
#pragma unroll
    for (int j = 0; j < KNN; ++j) h1_s[j][c] = fmaxf(fmaf(acc[j], bnscale, bec), 0.f);
    __syncthreads();

    float acc2[KNN];
    float b2c = b2[c];
#pragma unroll
    for (int j = 0; j < KNN; ++j) acc2[j] = b2c;
#pragma unroll
    for (int k = 0; k < 64; k += 4) {
        float w0 = W2[(k + 0) * 64 + c];
        float w1 = W2[(k + 1) * 64 + c];
        float w2 = W2[(k + 2) * 64 + c];
        float w3 = W2[(k + 3) * 64 + c];
#pragma unroll
        for (int j = 0; j < KNN; ++j) {
            float4 v = *(const float4*)&h1_s[j][k];
            acc2[j] = fmaf(v.x, w0, acc2[j]);
            acc2[j] = fmaf(v.y, w1, acc2[j]);
            acc2[j] = fmaf(v.z, w2, acc2[j]);
            acc2[j] = fmaf(v.w, w3, acc2[j]);
        }
    }
    float m = acc2[0];
#pragma unroll
    for (int j = 1; j < KNN; ++j) m = fmaxf(m, acc2[j]);
    out[(size_t)p * ldo + c] = m;
}

// ---------------------------------------------------------------- tiled fp32 GEMM: C = act(A@W + b)
template<int BM, int BN, int BK, bool RELU>
__global__ __launch_bounds__(256) void gemm_kernel(
    const float* __restrict__ A, int lda,
    const float* __restrict__ W,          // [K, N] row-major
    const float* __restrict__ bias,
    float* __restrict__ Cc, int ldc,
    int N, int K) {
    __shared__ __align__(16) float As[BK][BM];
    __shared__ __align__(16) float Bs[BK][BN];
    const int bm = blockIdx.y * BM;
    const int bn = blockIdx.x * BN;
    const int tid = threadIdx.x;
    const int tx = tid & 15, ty = tid >> 4;
    float acc[4][4] = {};
    for (int k0 = 0; k0 < K; k0 += BK) {
        {   // A tile: 64 rows x 16 cols, each thread float4
            int m = tid >> 2;
            int kq = (tid & 3) * 4;
            float4 v = *(const float4*)(A + (size_t)(bm + m) * lda + k0 + kq);
            As[kq + 0][m] = v.x; As[kq + 1][m] = v.y; As[kq + 2][m] = v.z; As[kq + 3][m] = v.w;
        }
        {   // W tile: 16 rows x 64 cols
            int kk = tid >> 4;
            int n4 = (tid & 15) * 4;
            float4 v = *(const float4*)(W + (size_t)(k0 + kk) * N + bn + n4);
            *(float4*)&Bs[kk][n4] = v;
        }
        __syncthreads();
#pragma unroll
        for (int kk = 0; kk < BK; ++kk) {
            float4 av = *(const float4*)&As[kk][ty * 4];
            float4 bv = *(const float4*)&Bs[kk][tx * 4];
            float a[4] = {av.x, av.y, av.z, av.w};
            float bb[4] = {bv.x, bv.y, bv.z, bv.w};
#pragma unroll
            for (int i = 0; i < 4; ++i)
#pragma unroll
                for (int j = 0; j < 4; ++j) acc[i][j] = fmaf(a[i], bb[j], acc[i][j]);
        }
        __syncthreads();
    }
#pragma unroll
    for (int i = 0; i < 4; ++i) {
        int m = bm + ty * 4 + i;
        float4 o;
        o.x = acc[i][0] + bias[bn + tx * 4 + 0];
        o.y = acc[i][1] + bias[bn + tx * 4 + 1];
        o.z = acc[i][2] + bias[bn + tx * 4 + 2];
        o.w = acc[i][3] + bias[bn + tx * 4 + 3];
        if (RELU) {
            o.x = fmaxf(o.x, 0.f); o.y = fmaxf(o.y, 0.f);
            o.z = fmaxf(o.z, 0.f); o.w = fmaxf(o.w, 0.f);
        }
        *(float4*)(Cc + (size_t)m * ldc + bn + tx * 4) = o;
    }
}

// ---------------------------------------------------------------- final layer (K=128 -> 40) + log_softmax
__global__ __launch_bounds__(64) void head_kernel(const float* __restrict__ h3,
                                                  const float* __restrict__ W4,
                                                  const float* __restrict__ b4,
                                                  float* __restrict__ out) {
    const int p = blockIdx.x;
    const int lane = threadIdx.x;
    const float* hp = h3 + (size_t)p * 128;
    float v = -INFINITY;
    if (lane < 40) {
        float acc = b4[lane];
#pragma unroll
        for (int k = 0; k < 128; ++k) acc = fmaf(hp[k], W4[k * 40 + lane], acc);
        v = acc;
    }
    float mx = v;
#pragma unroll
    for (int s = 1; s < 64; s <<= 1) mx = fmaxf(mx, __shfl_xor(mx, s));
    float e = (lane < 40) ? expf(v - mx) : 0.0f;
    float se = e;
#pragma unroll
    for (int s = 1; s < 64; s <<= 1) se += __shfl_xor(se, s);
    if (lane < 40) out[(size_t)p * 40 + lane] = v - mx - logf(se);
}

// ----------------------------------------------------------------
extern "C" void kernel_launch(void* const* d_in, const int* in_sizes, int n_in,
                              void* d_out, int out_size, void* d_ws, size_t ws_size,
                              hipStream_t stream) {
    (void)in_sizes; (void)n_in; (void)out_size; (void)ws_size;
    const float* x     = (const float*)d_in[0];
    const float* pos   = (const float*)d_in[1];
    const float* c1_W1 = (const float*)d_in[2];
    const float* c1_b1 = (const float*)d_in[3];
    const float* c1_g  = (const float*)d_in[4];
    const float* c1_be = (const float*)d_in[5];
    const float* c1_W2 = (const float*)d_in[6];
    const float* c1_b2 = (const float*)d_in[7];
    const float* c2_W1 = (const float*)d_in[8];
    const float* c2_b1 = (const float*)d_in[9];
    const float* c2_g  = (const float*)d_in[10];
    const float* c2_be = (const float*)d_in[11];
    const float* c2_W2 = (const float*)d_in[12];
    const float* c2_b2 = (const float*)d_in[13];
    const float* c3_W1 = (const float*)d_in[14];
    const float* c3_b1 = (const float*)d_in[15];
    const float* c3_g  = (const float*)d_in[16];
    const float* c3_be = (const float*)d_in[17];
    const float* c3_W2 = (const float*)d_in[18];
    const float* c3_b2 = (const float*)d_in[19];
    const float* m_W1  = (const float*)d_in[20];
    const float* m_b1  = (const float*)d_in[21];
    const float* m_W2  = (const float*)d_in[22];
    const float* m_b2  = (const float*)d_in[23];
    const float* m_W3  = (const float*)d_in[24];
    const float* m_b3  = (const float*)d_in[25];
    const float* m_W4  = (const float*)d_in[26];
    const float* m_b4  = (const float*)d_in[27];
    float* out = (float*)d_out;

    const int TOT = NB * NPTS;  // 32768

    // workspace layout (floats):
    float* ws   = (float*)d_ws;
    float* f0   = ws;                              // 196608
    int*   idxb = (int*)(ws + 196608);             // 655360 ints
    float* feat = ws + 196608 + 655360;            // 6291456  [32768 x 192]
    float* h1   = feat + 6291456;                  // 4194304  [4096 x 1024]
    float* h2   = h1 + 4194304;                    // 1048576  [4096 x 256]
    float* h3   = h2 + 1048576;                    // 524288   [4096 x 128]
    float* nrm  = h1;                              // alias: h1 only used in MLP phase

    concat_kernel<<<(TOT + 255) / 256, 256, 0, stream>>>(x, pos, f0, TOT);

    norm_kernel<6><<<(TOT + 255) / 256, 256, 0, stream>>>(f0, 6, nrm, TOT);
    knn_tile_kernel<6><<<TOT / 64, 256, 0, stream>>>(f0, 6, nrm, idxb);
    edgeconv_kernel<6><<<TOT, 64, 0, stream>>>(f0, 6, idxb,
        c1_W1, c1_b1, c1_g, c1_be, c1_W2, c1_b2, feat + 0, 192);

    norm_kernel<64><<<(TOT + 255) / 256, 256, 0, stream>>>(feat + 0, 192, nrm, TOT);
    knn_tile_kernel<64><<<TOT / 64, 256, 0, stream>>>(feat + 0, 192, nrm, idxb);
    edgeconv_kernel<64><<<TOT, 64, 0, stream>>>(feat + 0, 192, idxb,
        c2_W1, c2_b1, c2_g, c2_be, c2_W2, c2_b2, feat + 64, 192);

    norm_kernel<64><<<(TOT + 255) / 256, 256, 0, stream>>>(feat + 64, 192, nrm, TOT);
    knn_tile_kernel<64><<<TOT / 64, 256, 0, stream>>>(feat + 64, 192, nrm, idxb);
    edgeconv_kernel<64><<<TOT, 64, 0, stream>>>(feat + 64, 192, idxb,
        c3_W1, c3_b1, c3_g, c3_be, c3_W2, c3_b2, feat + 128, 192);

    const int MC = 4096;
    for (int mc = 0; mc < TOT; mc += MC) {
        gemm_kernel<64, 64, 16, true><<<dim3(1024 / 64, MC / 64), 256, 0, stream>>>(
            feat + (size_t)mc * 192, 192, m_W1, m_b1, h1, 1024, 1024, 192);
        gemm_kernel<64, 64, 16, true><<<dim3(256 / 64, MC / 64), 256, 0, stream>>>(
            h1, 1024, m_W2, m_b2, h2, 256, 256, 1024);
        gemm_kernel<64, 64, 16, true><<<dim3(128 / 64, MC / 64), 256, 0, stream>>>(
            h2, 256, m_W3, m_b3, h3, 128, 128, 256);
        head_kernel<<<MC, 64, 0, stream>>>(h3, m_W4, m_b4, out + (size_t)mc * 40);
    }
}

// Round 2
// 3088.899 us; speedup vs baseline: 3.7399x; 1.3564x over previous
//
#include <hip/hip_runtime.h>
#include <math.h>

#define KNN 20
#define NPTS 4096
#define NB 8

__device__ __forceinline__ bool lexless(float d1, int i1, float d2, int i2) {
    return d1 < d2 || (d1 == d2 && i1 < i2);
}

// ---------------------------------------------------------------- concat x|pos
__global__ __launch_bounds__(256) void concat_kernel(const float* __restrict__ x,
                                                     const float* __restrict__ pos,
                                                     float* __restrict__ f0, int total) {
    int p = blockIdx.x * 256 + threadIdx.x;
    if (p < total) {
        f0[(size_t)p*6 + 0] = x[(size_t)p*3 + 0];
        f0[(size_t)p*6 + 1] = x[(size_t)p*3 + 1];
        f0[(size_t)p*6 + 2] = x[(size_t)p*3 + 2];
        f0[(size_t)p*6 + 3] = pos[(size_t)p*3 + 0];
        f0[(size_t)p*6 + 4] = pos[(size_t)p*3 + 1];
        f0[(size_t)p*6 + 5] = pos[(size_t)p*3 + 2];
    }
}

// ---------------------------------------------------------------- squared norms
template<int C>
__global__ __launch_bounds__(256) void norm_kernel(const float* __restrict__ f, int ldf,
                                                   float* __restrict__ norms, int total) {
    int p = blockIdx.x * 256 + threadIdx.x;
    if (p >= total) return;
    const float* fp = f + (size_t)p * ldf;
    float s = 0.f;
    if constexpr ((C & 3) == 0) {
#pragma unroll
        for (int k = 0; k < C; k += 4) {
            float4 v = *(const float4*)(fp + k);
            s = fmaf(v.x, v.x, s); s = fmaf(v.y, v.y, s);
            s = fmaf(v.z, v.z, s); s = fmaf(v.w, v.w, s);
        }
    } else {
#pragma unroll
        for (int k = 0; k < C; ++k) s = fmaf(fp[k], fp[k], s);
    }
    norms[p] = s;
}

// Insert (cd_, ci_) into the sorted-by-lexless register list bd[]/bi[].
#define CHAIN_INSERT(cd_, ci_) do {                                      \
    float cd = (cd_); int ci = (ci_);                                    \
    _Pragma("unroll")                                                    \
    for (int t = 0; t < KNN; ++t) {                                      \
        bool sw = lexless(cd, ci, bd[t], bi[t]);                         \
        float nd = sw ? cd : bd[t]; int ni = sw ? ci : bi[t];            \
        float od = sw ? bd[t] : cd; int oi = sw ? bi[t] : ci;            \
        bd[t] = nd; bi[t] = ni; cd = od; ci = oi;                        \
    }                                                                    \
} while (0)

#define FLUSH_PENDING() do {                                             \
    if (cnt > 0) CHAIN_INSERT(p0d, p0i);                                 \
    if (cnt > 1) CHAIN_INSERT(p1d, p1i);                                 \
    if (cnt > 2) CHAIN_INSERT(p2d, p2i);                                 \
    if (cnt > 3) CHAIN_INSERT(p3d, p3i);                                 \
    cnt = 0;                                                             \
} while (0)

// ---------------------------------------------------------------- fused tiled kNN
// Block = 256 threads handles 64 queries of one batch.
// Loop over 64-candidate tiles: stage features, 64x64 dot GEMM (4x4 micro-tiles),
// distances to LDS, then 4 threads/query scan disjoint quarters. Qualifying
// candidates are pushed to a 4-deep register pending buffer (stale-threshold
// filter); the expensive 20-step insertion chain runs only at flushes.
template<int C>
__global__ __launch_bounds__(256) void knn_tile_kernel(const float* __restrict__ f, int ldf,
                                                       const float* __restrict__ norms,
                                                       int* __restrict__ idx) {
    const int q0    = blockIdx.x * 64;      // global query base
    const int b     = q0 >> 12;             // batch
    const int qloc0 = q0 & (NPTS - 1);
    const int tid   = threadIdx.x;
    const int tx    = tid & 15, ty = tid >> 4;

    union __align__(16) SM {
        struct {
            float Qs[C][64];
            float Cs[C][64];
            float Ds[64][65];
            float cn[64];
        } a;
        struct {
            float md[64][4 * KNN];
            int   mi[64][4 * KNN];
        } m;
    };
    __shared__ SM sm;

    const float* fb = f + (size_t)b * NPTS * ldf;

    // stage query tile Qs[k][m]
    if constexpr ((C & 3) == 0) {
        int m = tid >> 2, ko = (tid & 3) * 4;
        const float* src = fb + (size_t)(qloc0 + m) * ldf;
#pragma unroll
        for (int k4 = ko; k4 < C; k4 += 16) {
            float4 v = *(const float4*)(src + k4);
            sm.a.Qs[k4 + 0][m] = v.x; sm.a.Qs[k4 + 1][m] = v.y;
            sm.a.Qs[k4 + 2][m] = v.z; sm.a.Qs[k4 + 3][m] = v.w;
        }
    } else {
        for (int e = tid; e < C * 64; e += 256) {
            int k = e >> 6, m = e & 63;
            sm.a.Qs[k][m] = fb[(size_t)(qloc0 + m) * ldf + k];
        }
    }

    const float qnr = norms[q0 + (tid & 63)];   // own query's norm (qr = tid&63)

    float bd[KNN]; int bi[KNN];
#pragma unroll
    for (int t = 0; t < KNN; ++t) { bd[t] = INFINITY; bi[t] = 0x7fffffff; }

    // pending buffer (stale-threshold batched insertion)
    float p0d = INFINITY, p1d = INFINITY, p2d = INFINITY, p3d = INFINITY;
    int   p0i = 0, p1i = 0, p2i = 0, p3i = 0;
    int   cnt = 0;

    for (int j0 = 0; j0 < NPTS; j0 += 64) {
        __syncthreads();   // prev scan done / Qs staged before (re)filling Cs,cn

        // stage candidate tile Cs[k][j] + candidate norms
        if constexpr ((C & 3) == 0) {
            int j = tid >> 2, ko = (tid & 3) * 4;
            const float* src = fb + (size_t)(j0 + j) * ldf;
#pragma unroll
            for (int k4 = ko; k4 < C; k4 += 16) {
                float4 v = *(const float4*)(src + k4);
                sm.a.Cs[k4 + 0][j] = v.x; sm.a.Cs[k4 + 1][j] = v.y;
                sm.a.Cs[k4 + 2][j] = v.z; sm.a.Cs[k4 + 3][j] = v.w;
            }
        } else {
            for (int e = tid; e < C * 64; e += 256) {
                int k = e >> 6, j = e & 63;
                sm.a.Cs[k][j] = fb[(size_t)(j0 + j) * ldf + k];
            }
        }
        if (tid < 64) sm.a.cn[tid] = norms[(size_t)b * NPTS + j0 + tid];
        __syncthreads();

        // 64x64xC dot-product tile, 4x4 micro-tile per thread
        float acc[4][4] = {};
#pragma unroll 8
        for (int kk = 0; kk < C; ++kk) {
            float4 av = *(const float4*)&sm.a.Qs[kk][ty * 4];
            float4 bv = *(const float4*)&sm.a.Cs[kk][tx * 4];
            float a[4] = {av.x, av.y, av.z, av.w};
            float bb[4] = {bv.x, bv.y, bv.z, bv.w};
#pragma unroll
            for (int i = 0; i < 4; ++i)
#pragma unroll
                for (int j = 0; j < 4; ++j) acc[i][j] = fmaf(a[i], bb[j], acc[i][j]);
        }
#pragma unroll
        for (int i = 0; i < 4; ++i)
#pragma unroll
            for (int j = 0; j < 4; ++j)
                sm.a.Ds[ty * 4 + i][tx * 4 + j] = acc[i][j];
        __syncthreads();

        // scan: thread (grp, qr) checks candidates [grp*16, grp*16+16) of this tile.
        // Rolled loop: keeps only two instantiations of the insertion chain.
        {
            const int qr = tid & 63;
            const int jb = (tid >> 6) * 16;
#pragma unroll 1
            for (int jj = 0; jj < 16; ++jj) {
                float dot = sm.a.Ds[qr][jb + jj];
                float d   = qnr + sm.a.cn[jb + jj] - 2.0f * dot;
                int   jg  = j0 + jb + jj;
                if (lexless(d, jg, bd[KNN - 1], bi[KNN - 1])) {
                    p3d = p2d; p3i = p2i;
                    p2d = p1d; p2i = p1i;
                    p1d = p0d; p1i = p0i;
                    p0d = d;   p0i = jg;
                    ++cnt;
                }
                if (__any(cnt >= 4)) FLUSH_PENDING();
            }
            if (__any(cnt > 0)) FLUSH_PENDING();
        }
    }
    __syncthreads();   // all scans done; a.* dead → reuse as merge buffers

    {
        const int qr = tid & 63;
        const int grp = tid >> 6;
#pragma unroll
        for (int t = 0; t < KNN; ++t) {
            sm.m.md[qr][grp * KNN + t] = bd[t];
            sm.m.mi[qr][grp * KNN + t] = bi[t];
        }
    }
    __syncthreads();

    if (tid < 64) {
        // 4-way merge of sorted 20-lists (disjoint candidate subsets)
        int p0 = 0, p1 = KNN, p2 = 2 * KNN, p3 = 3 * KNN;
        int* op = idx + (size_t)(q0 + tid) * KNN;
        for (int r = 0; r < KNN; ++r) {
            float d0 = (p0 < KNN)     ? sm.m.md[tid][p0] : INFINITY;
            int   i0 = (p0 < KNN)     ? sm.m.mi[tid][p0] : 0x7fffffff;
            float d1 = (p1 < 2 * KNN) ? sm.m.md[tid][p1] : INFINITY;
            int   i1 = (p1 < 2 * KNN) ? sm.m.mi[tid][p1] : 0x7fffffff;
            float d2 = (p2 < 3 * KNN) ? sm.m.md[tid][p2] : INFINITY;
            int   i2 = (p2 < 3 * KNN) ? sm.m.mi[tid][p2] : 0x7fffffff;
            float d3 = (p3 < 4 * KNN) ? sm.m.md[tid][p3] : INFINITY;
            int   i3 = (p3 < 4 * KNN) ? sm.m.mi[tid][p3] : 0x7fffffff;
            float bdv = d0; int biv = i0; int bg = 0;
            if (lexless(d1, i1, bdv, biv)) { bdv = d1; biv = i1; bg = 1; }
            if (lexless(d2, i2, bdv, biv)) { bdv = d2; biv = i2; bg = 2; }
            if (lexless(d3, i3, bdv, biv)) { bdv = d3; biv = i3; bg = 3; }
            op[r] = biv;
            p0 += (bg == 0); p1 += (bg == 1); p2 += (bg == 2); p3 += (bg == 3);
        }
    }
}

// ---------------------------------------------------------------- EdgeConv (wave/point)
template<int C>
__global__ __launch_bounds__(64) void edgeconv_kernel(
    const float* __restrict__ f, int ldf,
    const int* __restrict__ idx,
    const float* __restrict__ W1, const float* __restrict__ b1,
    const float* __restrict__ g,  const float* __restrict__ be,
    const float* __restrict__ W2, const float* __restrict__ b2,
    float* __restrict__ out, int ldo) {
    const int p = blockIdx.x;
    const int b = p >> 12;
    const int i = p & (NPTS - 1);
    const int c = threadIdx.x;   // output channel, 0..63
    __shared__ __align__(16) float fi_s[C];
    __shared__ __align__(16) float fj_s[KNN][C];
    __shared__ __align__(16) float h1_s[KNN][64];
    __shared__ int nidx[KNN];
    const float* fb = f + (size_t)b * NPTS * ldf;
    if (c < KNN) nidx[c] = idx[(size_t)p * KNN + c];
    if (c < C)   fi_s[c] = fb[(size_t)i * ldf + c];
    __syncthreads();
#pragma unroll
    for (int j = 0; j < KNN; ++j)
        if (c < C) fj_s[j][c] = fb[(size_t)nidx[j] * ldf + c];
    __syncthreads();
    float fir[C];
#pragma unroll
    for (int k = 0; k < C; ++k) fir[k] = fi_s[k];

    const float bn_s = (float)(1.0 / sqrt(1.0 + 1e-5));
    const float bnscale = g[c] * bn_s;
    float base = b1[c];
#pragma unroll
    for (int k = 0; k < C; ++k) base = fmaf(fir[k], W1[k * 64 + c], base);
    float acc[KNN];
#pragma unroll
    for (int j = 0; j < KNN; ++j) acc[j] = base;

    if constexpr ((C & 3) == 0) {
#pragma unroll
        for (int k = 0; k < C; k += 4) {
            float w0 = W1[(C + k + 0) * 64 + c];
            float w1 = W1[(C + k + 1) * 64 + c];
            float w2 = W1[(C + k + 2) * 64 + c];
            float w3 = W1[(C + k + 3) * 64 + c];
            float f0 = fir[k + 0], f1 = fir[k + 1], f2 = fir[k + 2], f3 = fir[k + 3];
#pragma unroll
            for (int j = 0; j < KNN; ++j) {
                float4 v = *(const float4*)&fj_s[j][k];
                acc[j] = fmaf(v.x - f0, w0, acc[j]);
                acc[j] = fmaf(v.y - f1, w1, acc[j]);
                acc[j] = fmaf(v.z - f2, w2, acc[j]);
                acc[j] = fmaf(v.w - f3, w3, acc[j]);
            }
        }
    } else {
#pragma unroll
        for (int k = 0; k < C; ++k) {
            float w = W1[(C + k) * 64 + c];
            float fik = fir[k];
#pragma unroll
            for (int j = 0; j < KNN; ++j) acc[j] = fmaf(fj_s[j][k] - fik, w, acc[j]);
        }
    }
    float bec = be[c];
#pragma unroll
    for (int j = 0; j < KNN; ++j) h1_s[j][c] = fmaxf(fmaf(acc[j], bnscale, bec), 0.f);
    __syncthreads();

    float acc2[KNN];
    float b2c = b2[c];
#pragma unroll
    for (int j = 0; j < KNN; ++j) acc2[j] = b2c;
#pragma unroll
    for (int k = 0; k < 64; k += 4) {
        float w0 = W2[(k + 0) * 64 + c];
        float w1 = W2[(k + 1) * 64 + c];
        float w2 = W2[(k + 2) * 64 + c];
        float w3 = W2[(k + 3) * 64 + c];
#pragma unroll
        for (int j = 0; j < KNN; ++j) {
            float4 v = *(const float4*)&h1_s[j][k];
            acc2[j] = fmaf(v.x, w0, acc2[j]);
            acc2[j] = fmaf(v.y, w1, acc2[j]);
            acc2[j] = fmaf(v.z, w2, acc2[j]);
            acc2[j] = fmaf(v.w, w3, acc2[j]);
        }
    }
    float m = acc2[0];
#pragma unroll
    for (int j = 1; j < KNN; ++j) m = fmaxf(m, acc2[j]);
    out[(size_t)p * ldo + c] = m;
}

// ---------------------------------------------------------------- tiled fp32 GEMM: C = act(A@W + b)
template<int BM, int BN, int BK, bool RELU>
__global__ __launch_bounds__(256) void gemm_kernel(
    const float* __restrict__ A, int lda,
    const float* __restrict__ W,          // [K, N] row-major
    const float* __restrict__ bias,
    float* __restrict__ Cc, int ldc,
    int N, int K) {
    __shared__ __align__(16) float As[BK][BM];
    __shared__ __align__(16) float Bs[BK][BN];
    const int bm = blockIdx.y * BM;
    const int bn = blockIdx.x * BN;
    const int tid = threadIdx.x;
    const int tx = tid & 15, ty = tid >> 4;
    float acc[4][4] = {};
    for (int k0 = 0; k0 < K; k0 += BK) {
        {   // A tile: 64 rows x 16 cols, each thread float4
            int m = tid >> 2;
            int kq = (tid & 3) * 4;
            float4 v = *(const float4*)(A + (size_t)(bm + m) * lda + k0 + kq);
            As[kq + 0][m] = v.x; As[kq + 1][m] = v.y; As[kq + 2][m] = v.z; As[kq + 3][m] = v.w;
        }
        {   // W tile: 16 rows x 64 cols
            int kk = tid >> 4;
            int n4 = (tid & 15) * 4;
            float4 v = *(const float4*)(W + (size_t)(k0 + kk) * N + bn + n4);
            *(float4*)&Bs[kk][n4] = v;
        }
        __syncthreads();
#pragma unroll
        for (int kk = 0; kk < BK; ++kk) {
            float4 av = *(const float4*)&As[kk][ty * 4];
            float4 bv = *(const float4*)&Bs[kk][tx * 4];
            float a[4] = {av.x, av.y, av.z, av.w};
            float bb[4] = {bv.x, bv.y, bv.z, bv.w};
#pragma unroll
            for (int i = 0; i < 4; ++i)
#pragma unroll
                for (int j = 0; j < 4; ++j) acc[i][j] = fmaf(a[i], bb[j], acc[i][j]);
        }
        __syncthreads();
    }
#pragma unroll
    for (int i = 0; i < 4; ++i) {
        int m = bm + ty * 4 + i;
        float4 o;
        o.x = acc[i][0] + bias[bn + tx * 4 + 0];
        o.y = acc[i][1] + bias[bn + tx * 4 + 1];
        o.z = acc[i][2] + bias[bn + tx * 4 + 2];
        o.w = acc[i][3] + bias[bn + tx * 4 + 3];
        if (RELU) {
            o.x = fmaxf(o.x, 0.f); o.y = fmaxf(o.y, 0.f);
            o.z = fmaxf(o.z, 0.f); o.w = fmaxf(o.w, 0.f);
        }
        *(float4*)(Cc + (size_t)m * ldc + bn + tx * 4) = o;
    }
}

// ---------------------------------------------------------------- final layer (K=128 -> 40) + log_softmax
__global__ __launch_bounds__(64) void head_kernel(const float* __restrict__ h3,
                                                  const float* __restrict__ W4,
                                                  const float* __restrict__ b4,
                                                  float* __restrict__ out) {
    const int p = blockIdx.x;
    const int lane = threadIdx.x;
    const float* hp = h3 + (size_t)p * 128;
    float v = -INFINITY;
    if (lane < 40) {
        float acc = b4[lane];
#pragma unroll
        for (int k = 0; k < 128; ++k) acc = fmaf(hp[k], W4[k * 40 + lane], acc);
        v = acc;
    }
    float mx = v;
#pragma unroll
    for (int s = 1; s < 64; s <<= 1) mx = fmaxf(mx, __shfl_xor(mx, s));
    float e = (lane < 40) ? expf(v - mx) : 0.0f;
    float se = e;
#pragma unroll
    for (int s = 1; s < 64; s <<= 1) se += __shfl_xor(se, s);
    if (lane < 40) out[(size_t)p * 40 + lane] = v - mx - logf(se);
}

// ----------------------------------------------------------------
extern "C" void kernel_launch(void* const* d_in, const int* in_sizes, int n_in,
                              void* d_out, int out_size, void* d_ws, size_t ws_size,
                              hipStream_t stream) {
    (void)in_sizes; (void)n_in; (void)out_size; (void)ws_size;
    const float* x     = (const float*)d_in[0];
    const float* pos   = (const float*)d_in[1];
    const float* c1_W1 = (const float*)d_in[2];
    const float* c1_b1 = (const float*)d_in[3];
    const float* c1_g  = (const float*)d_in[4];
    const float* c1_be = (const float*)d_in[5];
    const float* c1_W2 = (const float*)d_in[6];
    const float* c1_b2 = (const float*)d_in[7];
    const float* c2_W1 = (const float*)d_in[8];
    const float* c2_b1 = (const float*)d_in[9];
    const float* c2_g  = (const float*)d_in[10];
    const float* c2_be = (const float*)d_in[11];
    const float* c2_W2 = (const float*)d_in[12];
    const float* c2_b2 = (const float*)d_in[13];
    const float* c3_W1 = (const float*)d_in[14];
    const float* c3_b1 = (const float*)d_in[15];
    const float* c3_g  = (const float*)d_in[16];
    const float* c3_be = (const float*)d_in[17];
    const float* c3_W2 = (const float*)d_in[18];
    const float* c3_b2 = (const float*)d_in[19];
    const float* m_W1  = (const float*)d_in[20];
    const float* m_b1  = (const float*)d_in[21];
    const float* m_W2  = (const float*)d_in[22];
    const float* m_b2  = (const float*)d_in[23];
    const float* m_W3  = (const float*)d_in[24];
    const float* m_b3  = (const float*)d_in[25];
    const float* m_W4  = (const float*)d_in[26];
    const float* m_b4  = (const float*)d_in[27];
    float* out = (float*)d_out;

    const int TOT = NB * NPTS;  // 32768

    // workspace layout (floats):
    float* ws   = (float*)d_ws;
    float* f0   = ws;                              // 196608
    int*   idxb = (int*)(ws + 196608);             // 655360 ints
    float* feat = ws + 196608 + 655360;            // 6291456  [32768 x 192]
    float* h1   = feat + 6291456;                  // 4194304  [4096 x 1024]
    float* h2   = h1 + 4194304;                    // 1048576  [4096 x 256]
    float* h3   = h2 + 1048576;                    // 524288   [4096 x 128]
    float* nrm  = h1;                              // alias: h1 only used in MLP phase

    concat_kernel<<<(TOT + 255) / 256, 256, 0, stream>>>(x, pos, f0, TOT);

    norm_kernel<6><<<(TOT + 255) / 256, 256, 0, stream>>>(f0, 6, nrm, TOT);
    knn_tile_kernel<6><<<TOT / 64, 256, 0, stream>>>(f0, 6, nrm, idxb);
    edgeconv_kernel<6><<<TOT, 64, 0, stream>>>(f0, 6, idxb,
        c1_W1, c1_b1, c1_g, c1_be, c1_W2, c1_b2, feat + 0, 192);

    norm_kernel<64><<<(TOT + 255) / 256, 256, 0, stream>>>(feat + 0, 192, nrm, TOT);
    knn_tile_kernel<64><<<TOT / 64, 256, 0, stream>>>(feat + 0, 192, nrm, idxb);
    edgeconv_kernel<64><<<TOT, 64, 0, stream>>>(feat + 0, 192, idxb,
        c2_W1, c2_b1, c2_g, c2_be, c2_W2, c2_b2, feat + 64, 192);

    norm_kernel<64><<<(TOT + 255) / 256, 256, 0, stream>>>(feat + 64, 192, nrm, TOT);
    knn_tile_kernel<64><<<TOT / 64, 256, 0, stream>>>(feat + 64, 192, nrm, idxb);
    edgeconv_kernel<64><<<TOT, 64, 0, stream>>>(feat + 64, 192, idxb,
        c3_W1, c3_b1, c3_g, c3_be, c3_W2, c3_b2, feat + 128, 192);

    const int MC = 4096;
    for (int mc = 0; mc < TOT; mc += MC) {
        gemm_kernel<64, 64, 16, true><<<dim3(1024 / 64, MC / 64), 256, 0, stream>>>(
            feat + (size_t)mc * 192, 192, m_W1, m_b1, h1, 1024, 1024, 192);
        gemm_kernel<64, 64, 16, true><<<dim3(256 / 64, MC / 64), 256, 0, stream>>>(
            h1, 1024, m_W2, m_b2, h2, 256, 256, 1024);
        gemm_kernel<64, 64, 16, true><<<dim3(128 / 64, MC / 64), 256, 0, stream>>>(
            h2, 256, m_W3, m_b3, h3, 128, 128, 256);
        head_kernel<<<MC, 64, 0, stream>>>(h3, m_W4, m_b4, out + (size_t)mc * 40);
    }
}